// Round 1
// 456.598 us; speedup vs baseline: 1.0011x; 1.0011x over previous
//
#include <hip/hip_runtime.h>
#include <hip/hip_bf16.h>

typedef __bf16 v8bf __attribute__((ext_vector_type(8)));
typedef __bf16 v4bf __attribute__((ext_vector_type(4)));
typedef float  v4f  __attribute__((ext_vector_type(4)));

#define AS1 __attribute__((address_space(1)))
#define AS3 __attribute__((address_space(3)))

static __device__ __forceinline__ void gload_lds16(const void* g, void* l) {
  __builtin_amdgcn_global_load_lds((const AS1 void*)g, (AS3 void*)l, 16, 0, 0);
}

// ---- elementwise fp32 -> bf16 (n multiple of 4) ----
__global__ __launch_bounds__(256)
void cvt_bf16(const float* __restrict__ in, __bf16* __restrict__ out, long n) {
  const long i = ((long)blockIdx.x * 256 + threadIdx.x) * 4;
  if (i >= n) return;
  v4f v = *(const v4f*)&in[i];
  v4bf o;
#pragma unroll
  for (int u = 0; u < 4; ++u) o[u] = (__bf16)v[u];
  *(v4bf*)&out[i] = o;
}

// ---- X [n][c][b] fp32 -> XT [n][b][c] bf16, 64x64 tiles via LDS ----
__global__ __launch_bounds__(256)
void cvt_transpose(const float* __restrict__ X, __bf16* __restrict__ XT) {
  __shared__ float t[64][65];
  const int b0 = blockIdx.x * 64, c0 = blockIdx.y * 64;
  const long n = blockIdx.z;
  const float* Xp = X + n * (1024L * 2048);
  __bf16* Tp = XT + n * (2048L * 1024);
  const int tid = threadIdx.x;
  const int r16 = tid >> 4, c4 = (tid & 15) * 4;
#pragma unroll
  for (int it = 0; it < 4; ++it) {
    const int r = r16 + it * 16;   // local c
    *(v4f*)&t[r][c4] = *(const v4f*)&Xp[(long)(c0 + r) * 2048 + b0 + c4];
  }
  __syncthreads();
  const int rb8 = tid >> 3, c8 = (tid & 7) * 8;
#pragma unroll
  for (int it = 0; it < 2; ++it) {
    const int rb = rb8 + it * 32;  // local b
    v8bf o;
#pragma unroll
    for (int u = 0; u < 8; ++u) o[u] = (__bf16)t[c8 + u][rb];
    *(v8bf*)&Tp[(long)(b0 + rb) * 1024 + c0 + c8] = o;
  }
}

// ---- 256x256 TN GEMM, 8 waves, BK=64, double-buffered LDS (128 KiB),
//      4-phase/K-tile schedule with counted vmcnt (never 0 in steady state),
//      T2 XOR-swizzled LDS (slot ^= row&7 on 16B slots), T5 setprio.
// out[m,n] = sum_k A[m,k]*B[n,k]  (both row stride = KD)
// EPI 0: += bias[col], clamp +-32 ; EPI 1: *= rsqrt(max(dk2[row]*dq2[col],eps)),
// clamp +-4 ; EPI 2: clamp +-1.
template<int KD, int EPI, typename OT>
__global__ __launch_bounds__(512, 2)
void gemm256(const __bf16* __restrict__ Abase, const __bf16* __restrict__ Bbase,
             OT* __restrict__ Obase, const __bf16* __restrict__ bias,
             const float* __restrict__ dk2, const float* __restrict__ dq2,
             long sA, long sB, long sO) {
  // [buf0: A(16384) B(16384)][buf1: A B]  = 65536 bf16 = 128 KiB
  __shared__ __align__(128) __bf16 lds[65536];

  const int tid  = threadIdx.x;
  const int wave = tid >> 6, lane = tid & 63;
  const int wr = wave >> 2, wc = wave & 3;     // 2 x 4 wave grid
  const int fr = lane & 15, q = lane >> 4;
  const int f7 = fr & 7;

  const int n0 = blockIdx.x * 256, m0 = blockIdx.y * 256;
  const long z = blockIdx.z;

  const __bf16* A = Abase + z * sA + (long)m0 * KD;
  const __bf16* B = Bbase + z * sB + (long)n0 * KD;

  // staging: round i covers 16B-slots [i*512 + tid]; slot s -> row s>>3, sl s&7
  // stored swizzled: data at slot (row, sl) = global k-chunk (sl ^ (row&7))
  const int srow = tid >> 3;
  const int scol = ((tid & 7) ^ (srow & 7)) << 3;   // pre-swizzled source chunk
  const __bf16* gA = A + (long)srow * KD + scol;
  const __bf16* gB = B + (long)srow * KD + scol;
  const int ldsbase = wave * 512;   // elems; round i adds i*4096

  auto stage4 = [&](const __bf16* g, __bf16* l, int kt) {
    const __bf16* gp = g + kt * 64;
#pragma unroll
    for (int i = 0; i < 4; ++i)
      gload_lds16(gp + (long)i * 64 * KD, l + i * 4096 + ldsbase);
  };
  auto stage2 = [&](const __bf16* g, __bf16* l, int kt, int i0) {
    const __bf16* gp = g + kt * 64;
#pragma unroll
    for (int i = i0; i < 4; i += 2)
      gload_lds16(gp + (long)i * 64 * KD, l + i * 4096 + ldsbase);
  };

  v4f acc[8][4];
#pragma unroll
  for (int i = 0; i < 8; ++i)
#pragma unroll
    for (int j = 0; j < 4; ++j) acc[i][j] = {0.f, 0.f, 0.f, 0.f};

  const int rowA = wr * 128 + fr;         // + i*16
  const int rowB = wc * 64 + fr;          // + j*16
  const int offk = (q ^ f7) << 3;         // ks=0 swizzled slot offset (elems)

  constexpr int NT = KD / 64;
  // prologue: tiles 0 and 1 in flight; wait for tile 0 (8 oldest)
  stage4(gA, lds, 0);
  stage4(gB, lds + 16384, 0);
  stage4(gA, lds + 32768, 1);
  stage4(gB, lds + 49152, 1);
  asm volatile("s_waitcnt vmcnt(8)" ::: "memory");
  __builtin_amdgcn_s_barrier();
  __builtin_amdgcn_sched_barrier(0);

#pragma unroll 1
  for (int t = 0; t < NT; ++t) {
    const int cur = t & 1;
    __bf16* sa = lds + cur * 32768;
    __bf16* sb = sa + 16384;

    // all B fragments for this K-tile (held in regs across the 4 phases)
    v8bf bfr[4][2];
#pragma unroll
    for (int j = 0; j < 4; ++j) {
      const int rb = (rowB + j * 16) * 64 + offk;
      bfr[j][0] = *(const v8bf*)&sb[rb];
      bfr[j][1] = *(const v8bf*)&sb[rb ^ 32];
    }

#pragma unroll
    for (int p = 0; p < 4; ++p) {
      v8bf af[2][2];
#pragma unroll
      for (int u = 0; u < 2; ++u) {
        const int ra = (rowA + (2 * p + u) * 16) * 64 + offk;
        af[u][0] = *(const v8bf*)&sa[ra];
        af[u][1] = *(const v8bf*)&sa[ra ^ 32];
      }
      // prefetch tile t+2 into regions of buf[cur] already fully consumed:
      // B fully read in phase 0; A rounds {0,2} (rows 0-63,128-191) after ph1.
      if (p == 1 && t + 2 < NT) stage4(gB, sb, t + 2);
      if (p == 2 && t + 2 < NT) stage2(gA, sa, t + 2, 0);
      __builtin_amdgcn_s_barrier();
      __builtin_amdgcn_s_setprio(1);
#pragma unroll
      for (int ks = 0; ks < 2; ++ks)
#pragma unroll
        for (int u = 0; u < 2; ++u)
#pragma unroll
          for (int j = 0; j < 4; ++j)
            acc[2 * p + u][j] = __builtin_amdgcn_mfma_f32_16x16x32_bf16(
                af[u][ks], bfr[j][ks], acc[2 * p + u][j], 0, 0, 0);
      __builtin_amdgcn_s_setprio(0);
      __builtin_amdgcn_s_barrier();
    }

    // tail: A rounds {1,3} (rows 64-127,192-255) now consumed; counted vmcnt
    // leaves tile t+2's 8 loads in flight while guaranteeing tile t+1 landed.
    if (t + 2 < NT) {
      stage2(gA, sa, t + 2, 1);
      asm volatile("s_waitcnt vmcnt(8)" ::: "memory");
    } else if (t + 2 == NT) {
      asm volatile("s_waitcnt vmcnt(0)" ::: "memory");
    }
    __builtin_amdgcn_s_barrier();
    __builtin_amdgcn_sched_barrier(0);
  }

  OT* O = Obase + z * sO;
  const int ldo = gridDim.x * 256;
#pragma unroll
  for (int j = 0; j < 4; ++j) {
    const int col = n0 + wc * 64 + j * 16 + fr;
    float cv = 0.f;
    if (EPI == 0) cv = (float)bias[col];
    if (EPI == 1) cv = dq2[z * 2048 + col];
#pragma unroll
    for (int i = 0; i < 8; ++i) {
      const int row0 = m0 + wr * 128 + i * 16 + q * 4;
#pragma unroll
      for (int r = 0; r < 4; ++r) {
        float v = acc[i][j][r];
        const int row = row0 + r;
        if (EPI == 0) v = fminf(fmaxf(v + cv, -32.f), 32.f);
        if (EPI == 1) {
          v *= rsqrtf(fmaxf(dk2[z * 2048 + row] * cv, 1e-12f));
          v = fminf(fmaxf(v, -4.f), 4.f);
        }
        if (EPI == 2) v = fminf(fmaxf(v, -1.f), 1.f);
        O[(long)row * ldo + col] = (OT)v;
      }
    }
  }
}

// ---- row sum-of-squares: contiguous rows of 1024 bf16 -> out[row] ----
__global__ __launch_bounds__(256)
void rownorm2(const __bf16* __restrict__ T, float* __restrict__ out) {
  const int tid = threadIdx.x;
  const long row = (long)blockIdx.y * gridDim.x + blockIdx.x;
  const __bf16* p = T + row * 1024;
  v4bf v = *(const v4bf*)&p[tid * 4];
  float s = 0.f;
#pragma unroll
  for (int u = 0; u < 4; ++u) { float f = (float)v[u]; s += f * f; }
#pragma unroll
  for (int off = 32; off > 0; off >>= 1) s += __shfl_down(s, off);
  __shared__ float red[4];
  if ((tid & 63) == 0) red[tid >> 6] = s;
  __syncthreads();
  if (tid == 0) out[row] = red[0] + red[1] + red[2] + red[3];
}

// ---- in-place row softmax over 2048 bf16 (|Y|<=4: no max pass) ----
__global__ __launch_bounds__(256)
void softmax_rows(__bf16* __restrict__ Y) {
  const int tid = threadIdx.x;
  const long row = (long)blockIdx.y * gridDim.x + blockIdx.x;
  __bf16* p = Y + row * 2048;
  v8bf v = *(const v8bf*)&p[tid * 8];
  float f[8];
  float s = 0.f;
#pragma unroll
  for (int u = 0; u < 8; ++u) { f[u] = __expf((float)v[u]); s += f[u]; }
#pragma unroll
  for (int off = 32; off > 0; off >>= 1) s += __shfl_down(s, off);
  __shared__ float red[4];
  __shared__ float stot;
  if ((tid & 63) == 0) red[tid >> 6] = s;
  __syncthreads();
  if (tid == 0) stot = 1.f / (red[0] + red[1] + red[2] + red[3]);
  __syncthreads();
  const float inv = stot;
  v8bf o;
#pragma unroll
  for (int u = 0; u < 8; ++u) o[u] = (__bf16)(f[u] * inv);
  *(v8bf*)&p[tid * 8] = o;
}

extern "C" void kernel_launch(void* const* d_in, const int* in_sizes, int n_in,
                              void* d_out, int out_size, void* d_ws, size_t ws_size,
                              hipStream_t stream) {
  const float* X    = (const float*)d_in[0];
  const float* Wk_w = (const float*)d_in[1];
  const float* Wk_b = (const float*)d_in[2];
  const float* Wq_w = (const float*)d_in[3];
  const float* Wq_b = (const float*)d_in[4];
  float* out = (float*)d_out;

  // ws: [0,32M): XT bf16 [n][b][c] -> later Xbf bf16 [n][c][b]
  //     [32M,96M): YT bf16 [n][k][b]
  //     [96M+): DK2, DQ2, Wk_bf, Wq_bf, bk_bf, bq_bf
  char* ws = (char*)d_ws;
  __bf16* XT  = (__bf16*)(ws);
  __bf16* Xbf = (__bf16*)(ws);
  __bf16* YT  = (__bf16*)(ws + 33554432L);
  char* aux   = ws + 100663296L;
  float*  DK2   = (float*)(aux);
  float*  DQ2   = (float*)(aux + 65536L);
  __bf16* Wk_bf = (__bf16*)(aux + 131072L);
  __bf16* Wq_bf = (__bf16*)(aux + 131072L + 2097152L);
  __bf16* bk_bf = (__bf16*)(aux + 131072L + 4194304L);
  __bf16* bq_bf = (__bf16*)(aux + 131072L + 4196352L);
  // d_out (64 MiB) holds KT|QT until GEMM3 overwrites it with Z.
  __bf16* KT = (__bf16*)d_out;
  __bf16* QT = (__bf16*)((char*)d_out + 33554432L);

  // 0) convert weights/biases to bf16
  cvt_bf16<<<1024, 256, 0, stream>>>(Wk_w, Wk_bf, 1048576L);
  cvt_bf16<<<1024, 256, 0, stream>>>(Wq_w, Wq_bf, 1048576L);
  cvt_bf16<<<1, 256, 0, stream>>>(Wk_b, bk_bf, 1024L);
  cvt_bf16<<<1, 256, 0, stream>>>(Wq_b, bq_bf, 1024L);
  // 1) XT[n][b][c] = (bf16) X[n][c][b]
  cvt_transpose<<<dim3(32, 16, 8), 256, 0, stream>>>(X, XT);
  // 2) KT[n][b][o] = XT[b,:]·Wk[o,:] + bk[o]; same for QT
  gemm256<1024, 0, __bf16><<<dim3(4, 8, 8), 512, 0, stream>>>(
      XT, Wk_bf, KT, bk_bf, nullptr, nullptr, 2048L * 1024, 0L, 2048L * 1024);
  gemm256<1024, 0, __bf16><<<dim3(4, 8, 8), 512, 0, stream>>>(
      XT, Wq_bf, QT, bq_bf, nullptr, nullptr, 2048L * 1024, 0L, 2048L * 1024);
  // 3) Xbf = (bf16) X  (XT dead; same ws region)
  cvt_bf16<<<16384, 256, 0, stream>>>(X, Xbf, 16777216L);
  // 4) DK2[n][b] = |KT[b,:]|^2 ; DQ2 likewise
  rownorm2<<<dim3(2048, 8), 256, 0, stream>>>(KT, DK2);
  rownorm2<<<dim3(2048, 8), 256, 0, stream>>>(QT, DQ2);
  // 5) YT[n][k][b] = (KT[k,:]·QT[b,:]) * rsqrt(max(DK2[k]*DQ2[b],eps))
  gemm256<1024, 1, __bf16><<<dim3(8, 8, 8), 512, 0, stream>>>(
      KT, QT, YT, nullptr, DK2, DQ2, 2048L * 1024, 2048L * 1024, 2048L * 2048);
  // 6) softmax over b within each YT row (ref softmax over query axis)
  softmax_rows<<<dim3(2048, 8), 256, 0, stream>>>(YT);
  // 7) Z[n][c][k] = Xbf[c,:]·SMT[k,:]  (sum over b) -> d_out fp32
  gemm256<2048, 2, float><<<dim3(8, 4, 8), 512, 0, stream>>>(
      Xbf, YT, out, nullptr, nullptr, nullptr, 1024L * 2048, 2048L * 2048, 1024L * 2048);
}

// Round 2
// 404.681 us; speedup vs baseline: 1.1296x; 1.1283x over previous
//
#include <hip/hip_runtime.h>
#include <hip/hip_bf16.h>

typedef __bf16 v8bf __attribute__((ext_vector_type(8)));
typedef __bf16 v4bf __attribute__((ext_vector_type(4)));
typedef float  v4f  __attribute__((ext_vector_type(4)));

#define AS1 __attribute__((address_space(1)))
#define AS3 __attribute__((address_space(3)))

static __device__ __forceinline__ void gload_lds16(const void* g, void* l) {
  __builtin_amdgcn_global_load_lds((const AS1 void*)g, (AS3 void*)l, 16, 0, 0);
}

// ---- elementwise fp32 -> bf16 (n multiple of 4) ----
__global__ __launch_bounds__(256)
void cvt_bf16(const float* __restrict__ in, __bf16* __restrict__ out, long n) {
  const long i = ((long)blockIdx.x * 256 + threadIdx.x) * 4;
  if (i >= n) return;
  v4f v = *(const v4f*)&in[i];
  v4bf o;
#pragma unroll
  for (int u = 0; u < 4; ++u) o[u] = (__bf16)v[u];
  *(v4bf*)&out[i] = o;
}

// ---- X [n][c][b] fp32 -> XT [n][b][c] bf16, 64x64 tiles via LDS ----
__global__ __launch_bounds__(256)
void cvt_transpose(const float* __restrict__ X, __bf16* __restrict__ XT) {
  __shared__ float t[64][65];
  const int b0 = blockIdx.x * 64, c0 = blockIdx.y * 64;
  const long n = blockIdx.z;
  const float* Xp = X + n * (1024L * 2048);
  __bf16* Tp = XT + n * (2048L * 1024);
  const int tid = threadIdx.x;
  const int r16 = tid >> 4, c4 = (tid & 15) * 4;
#pragma unroll
  for (int it = 0; it < 4; ++it) {
    const int r = r16 + it * 16;   // local c
    *(v4f*)&t[r][c4] = *(const v4f*)&Xp[(long)(c0 + r) * 2048 + b0 + c4];
  }
  __syncthreads();
  const int rb8 = tid >> 3, c8 = (tid & 7) * 8;
#pragma unroll
  for (int it = 0; it < 2; ++it) {
    const int rb = rb8 + it * 32;  // local b
    v8bf o;
#pragma unroll
    for (int u = 0; u < 8; ++u) o[u] = (__bf16)t[c8 + u][rb];
    *(v8bf*)&Tp[(long)(b0 + rb) * 1024 + c0 + c8] = o;
  }
}

// ---- 256x256 TN GEMM, m201-style 8-phase schedule ----
// 8 waves (4x2), BK=64, 2 K-tiles per iter in 2 LDS buffers (128 KiB).
// Per phase: {ds_read one operand-half; stage one half-tile (2 gloads);
// barrier; lgkmcnt(0); setprio(1); 16 MFMA; setprio(0); barrier}.
// vmcnt(6) only at phase-4/8 ends (3 half-tiles in flight).
// LDS XOR-swizzle on 16B slots (slot ^= row&7) via pre-swizzled global src.
// out[m,n] = sum_k A[m,k]*B[n,k]  (both row stride = KD)
// EPI 0: += bias[col], clamp +-32 ; EPI 1: *= rsqrt(max(dk2[row]*dq2[col],eps)),
// clamp +-4 ; EPI 2: clamp +-1.
#define BAR __builtin_amdgcn_s_barrier()
#define LGKM0 do { asm volatile("s_waitcnt lgkmcnt(0)" ::: "memory"); \
                   __builtin_amdgcn_sched_barrier(0); } while (0)
#define VMW6 do { asm volatile("s_waitcnt vmcnt(6)" ::: "memory"); \
                  __builtin_amdgcn_sched_barrier(0); } while (0)
#define VMW0 do { asm volatile("s_waitcnt vmcnt(0)" ::: "memory"); \
                  __builtin_amdgcn_sched_barrier(0); } while (0)
#define MM(HM, HN) do { \
  __builtin_amdgcn_s_setprio(1); \
  _Pragma("unroll") for (int ks = 0; ks < 2; ++ks) \
  _Pragma("unroll") for (int u = 0; u < 2; ++u) \
  _Pragma("unroll") for (int j = 0; j < 4; ++j) \
    acc[2 * (HM) + u][4 * (HN) + j] = __builtin_amdgcn_mfma_f32_16x16x32_bf16( \
        af[u][ks], bfr[j][ks], acc[2 * (HM) + u][4 * (HN) + j], 0, 0, 0); \
  __builtin_amdgcn_s_setprio(0); } while (0)

template<int KD, int EPI, typename OT>
__global__ __launch_bounds__(512, 2)
void gemm256(const __bf16* __restrict__ Abase, const __bf16* __restrict__ Bbase,
             OT* __restrict__ Obase, const __bf16* __restrict__ bias,
             const float* __restrict__ dk2, const float* __restrict__ dq2,
             long sA, long sB, long sO) {
  // buf0 (even tiles): A[256][64] @0, B @16384; buf1 (odd tiles) @32768.
  __shared__ __align__(128) __bf16 lds[65536];

  const int tid = threadIdx.x;
  const int wave = tid >> 6, lane = tid & 63;
  const int qr = wave >> 1, qc = wave & 1;      // 4x2 wave grid per quadrant
  const int fr = lane & 15, q = lane >> 4;
  const int f7 = fr & 7;

  const int n0 = blockIdx.x * 256, m0 = blockIdx.y * 256;
  const long z = blockIdx.z;

  const __bf16* A = Abase + z * sA + (long)m0 * KD;
  const __bf16* B = Bbase + z * sB + (long)n0 * KD;

  // staging: wave w, instr i covers rows [half*128 + w*16 + i*8, +8);
  // lane l -> row +(l>>3), stores k-chunk ((l&7)^(l>>3)) at slot (l&7) (linear
  // LDS dest = l*16B from wave base -> swizzle lives in the SOURCE address).
  const int lrow = wave * 16 + (lane >> 3);
  const int lchunk = ((lane & 7) ^ (lane >> 3)) << 3;
  const __bf16* Alane = A + (long)lrow * KD + lchunk;
  const __bf16* Blane = B + (long)lrow * KD + lchunk;
  const int dbase = wave * 1024;   // elems within a half region (8192 elems)

  auto stage = [&](int kt, int isB, int half) {
    const __bf16* gp = (isB ? Blane : Alane) + (long)(half * 128) * KD + kt * 64;
    __bf16* dp = lds + (kt & 1) * 32768 + isB * 16384 + half * 8192 + dbase;
    gload_lds16(gp, dp);
    gload_lds16(gp + (long)8 * KD, dp + 512);
  };

  v4f acc[4][8];
#pragma unroll
  for (int i = 0; i < 4; ++i)
#pragma unroll
    for (int j = 0; j < 8; ++j) acc[i][j] = {0.f, 0.f, 0.f, 0.f};

  v8bf af[2][2], bfr[4][2];
  auto readA = [&](const __bf16* sa, int hm) {
#pragma unroll
    for (int u = 0; u < 2; ++u) {
      const int rb = (hm * 128 + qr * 32 + u * 16 + fr) * 64;
      af[u][0] = *(const v8bf*)&sa[rb + ((q ^ f7) << 3)];
      af[u][1] = *(const v8bf*)&sa[rb + (((q | 4) ^ f7) << 3)];
    }
  };
  auto readB = [&](const __bf16* sb, int hn) {
#pragma unroll
    for (int j = 0; j < 4; ++j) {
      const int rb = (hn * 128 + qc * 64 + j * 16 + fr) * 64;
      bfr[j][0] = *(const v8bf*)&sb[rb + ((q ^ f7) << 3)];
      bfr[j][1] = *(const v8bf*)&sb[rb + (((q | 4) ^ f7) << 3)];
    }
  };

  constexpr int NT = KD / 64;
  constexpr int NI = NT / 2;
  __bf16* s0 = lds;            // even-tile buffer
  __bf16* s1 = lds + 32768;    // odd-tile buffer

  // prologue: tile0 {A0,B0,B1,A1} + tile1 {A0,B1,A1}; tile1.B0 staged at ph1.
  stage(0, 0, 0); stage(0, 1, 0); stage(0, 1, 1); stage(0, 0, 1);
  stage(1, 0, 0); stage(1, 1, 1); stage(1, 0, 1);
  VMW6; BAR;

#pragma unroll 1
  for (int m = 0; m < NI; ++m) {
    const int T1 = 2 * m + 1, T2 = 2 * m + 2, T3 = 2 * m + 3;
    const bool nl = (m != NI - 1);   // not last iter
    // ph1: quad(0,0) of T0
    readA(s0, 0); readB(s0 + 16384, 0);
    stage(T1, 1, 0);
    BAR; LGKM0; MM(0, 0); BAR;
    // ph2: quad(0,1) — A0 held
    readB(s0 + 16384, 1);
    if (nl) stage(T2, 0, 0);
    BAR; LGKM0; MM(0, 1); BAR;
    // ph3: quad(1,1) — B1 held
    readA(s0, 1);
    if (nl) stage(T2, 1, 1);
    BAR; LGKM0; MM(1, 1); BAR;
    // ph4: quad(1,0) — A1 held
    readB(s0 + 16384, 0);
    if (nl) stage(T2, 0, 1);
    BAR; LGKM0; MM(1, 0);
    if (nl) { VMW6; } else { VMW0; }
    BAR;
    // ph5: quad(0,0) of T1
    readA(s1, 0); readB(s1 + 16384, 0);
    if (nl) stage(T2, 1, 0);
    BAR; LGKM0; MM(0, 0); BAR;
    // ph6
    readB(s1 + 16384, 1);
    if (nl) stage(T3, 0, 0);
    BAR; LGKM0; MM(0, 1); BAR;
    // ph7
    readA(s1, 1);
    if (nl) stage(T3, 1, 1);
    BAR; LGKM0; MM(1, 1); BAR;
    // ph8
    readB(s1 + 16384, 0);
    if (nl) stage(T3, 0, 1);
    BAR; LGKM0; MM(1, 0);
    if (nl) { VMW6; } else { VMW0; }
    BAR;
  }

  OT* O = Obase + z * sO;
  const int ldo = gridDim.x * 256;
#pragma unroll
  for (int bj = 0; bj < 8; ++bj) {
    const int col = n0 + (bj >> 2) * 128 + qc * 64 + (bj & 3) * 16 + fr;
    float cv = 0.f;
    if (EPI == 0) cv = (float)bias[col];
    if (EPI == 1) cv = dq2[z * 2048 + col];
#pragma unroll
    for (int ai = 0; ai < 4; ++ai) {
      const int row0 = m0 + (ai >> 1) * 128 + qr * 32 + (ai & 1) * 16 + q * 4;
#pragma unroll
      for (int r = 0; r < 4; ++r) {
        float v = acc[ai][bj][r];
        const int row = row0 + r;
        if (EPI == 0) v = fminf(fmaxf(v + cv, -32.f), 32.f);
        if (EPI == 1) {
          v *= rsqrtf(fmaxf(dk2[z * 2048 + row] * cv, 1e-12f));
          v = fminf(fmaxf(v, -4.f), 4.f);
        }
        if (EPI == 2) v = fminf(fmaxf(v, -1.f), 1.f);
        O[(long)row * ldo + col] = (OT)v;
      }
    }
  }
}

// ---- row sum-of-squares: contiguous rows of 1024 bf16 -> out[row] ----
__global__ __launch_bounds__(256)
void rownorm2(const __bf16* __restrict__ T, float* __restrict__ out) {
  const int tid = threadIdx.x;
  const long row = (long)blockIdx.y * gridDim.x + blockIdx.x;
  const __bf16* p = T + row * 1024;
  v4bf v = *(const v4bf*)&p[tid * 4];
  float s = 0.f;
#pragma unroll
  for (int u = 0; u < 4; ++u) { float f = (float)v[u]; s += f * f; }
#pragma unroll
  for (int off = 32; off > 0; off >>= 1) s += __shfl_down(s, off);
  __shared__ float red[4];
  if ((tid & 63) == 0) red[tid >> 6] = s;
  __syncthreads();
  if (tid == 0) out[row] = red[0] + red[1] + red[2] + red[3];
}

// ---- in-place row softmax over 2048 bf16 (|Y|<=4: no max pass) ----
__global__ __launch_bounds__(256)
void softmax_rows(__bf16* __restrict__ Y) {
  const int tid = threadIdx.x;
  const long row = (long)blockIdx.y * gridDim.x + blockIdx.x;
  __bf16* p = Y + row * 2048;
  v8bf v = *(const v8bf*)&p[tid * 8];
  float f[8];
  float s = 0.f;
#pragma unroll
  for (int u = 0; u < 8; ++u) { f[u] = __expf((float)v[u]); s += f[u]; }
#pragma unroll
  for (int off = 32; off > 0; off >>= 1) s += __shfl_down(s, off);
  __shared__ float red[4];
  __shared__ float stot;
  if ((tid & 63) == 0) red[tid >> 6] = s;
  __syncthreads();
  if (tid == 0) stot = 1.f / (red[0] + red[1] + red[2] + red[3]);
  __syncthreads();
  const float inv = stot;
  v8bf o;
#pragma unroll
  for (int u = 0; u < 8; ++u) o[u] = (__bf16)(f[u] * inv);
  *(v8bf*)&p[tid * 8] = o;
}

extern "C" void kernel_launch(void* const* d_in, const int* in_sizes, int n_in,
                              void* d_out, int out_size, void* d_ws, size_t ws_size,
                              hipStream_t stream) {
  const float* X    = (const float*)d_in[0];
  const float* Wk_w = (const float*)d_in[1];
  const float* Wk_b = (const float*)d_in[2];
  const float* Wq_w = (const float*)d_in[3];
  const float* Wq_b = (const float*)d_in[4];
  float* out = (float*)d_out;

  // ws: [0,32M): XT bf16 [n][b][c] -> later Xbf bf16 [n][c][b]
  //     [32M,96M): YT bf16 [n][k][b]
  //     [96M+): DK2, DQ2, Wk_bf, Wq_bf, bk_bf, bq_bf
  char* ws = (char*)d_ws;
  __bf16* XT  = (__bf16*)(ws);
  __bf16* Xbf = (__bf16*)(ws);
  __bf16* YT  = (__bf16*)(ws + 33554432L);
  char* aux   = ws + 100663296L;
  float*  DK2   = (float*)(aux);
  float*  DQ2   = (float*)(aux + 65536L);
  __bf16* Wk_bf = (__bf16*)(aux + 131072L);
  __bf16* Wq_bf = (__bf16*)(aux + 131072L + 2097152L);
  __bf16* bk_bf = (__bf16*)(aux + 131072L + 4194304L);
  __bf16* bq_bf = (__bf16*)(aux + 131072L + 4196352L);
  // d_out (64 MiB) holds KT|QT until GEMM3 overwrites it with Z.
  __bf16* KT = (__bf16*)d_out;
  __bf16* QT = (__bf16*)((char*)d_out + 33554432L);

  // 0) convert weights/biases to bf16
  cvt_bf16<<<1024, 256, 0, stream>>>(Wk_w, Wk_bf, 1048576L);
  cvt_bf16<<<1024, 256, 0, stream>>>(Wq_w, Wq_bf, 1048576L);
  cvt_bf16<<<1, 256, 0, stream>>>(Wk_b, bk_bf, 1024L);
  cvt_bf16<<<1, 256, 0, stream>>>(Wq_b, bq_bf, 1024L);
  // 1) XT[n][b][c] = (bf16) X[n][c][b]
  cvt_transpose<<<dim3(32, 16, 8), 256, 0, stream>>>(X, XT);
  // 2) KT[n][b][o] = XT[b,:]·Wk[o,:] + bk[o]; same for QT
  gemm256<1024, 0, __bf16><<<dim3(4, 8, 8), 512, 0, stream>>>(
      XT, Wk_bf, KT, bk_bf, nullptr, nullptr, 2048L * 1024, 0L, 2048L * 1024);
  gemm256<1024, 0, __bf16><<<dim3(4, 8, 8), 512, 0, stream>>>(
      XT, Wq_bf, QT, bq_bf, nullptr, nullptr, 2048L * 1024, 0L, 2048L * 1024);
  // 3) Xbf = (bf16) X  (XT dead; same ws region)
  cvt_bf16<<<16384, 256, 0, stream>>>(X, Xbf, 16777216L);
  // 4) DK2[n][b] = |KT[b,:]|^2 ; DQ2 likewise
  rownorm2<<<dim3(2048, 8), 256, 0, stream>>>(KT, DK2);
  rownorm2<<<dim3(2048, 8), 256, 0, stream>>>(QT, DQ2);
  // 5) YT[n][k][b] = (KT[k,:]·QT[b,:]) * rsqrt(max(DK2[k]*DQ2[b],eps))
  gemm256<1024, 1, __bf16><<<dim3(8, 8, 8), 512, 0, stream>>>(
      KT, QT, YT, nullptr, DK2, DQ2, 2048L * 1024, 2048L * 1024, 2048L * 2048);
  // 6) softmax over b within each YT row (ref softmax over query axis)
  softmax_rows<<<dim3(2048, 8), 256, 0, stream>>>(YT);
  // 7) Z[n][c][k] = Xbf[c,:]·SMT[k,:]  (sum over b) -> d_out fp32
  gemm256<2048, 2, float><<<dim3(8, 4, 8), 512, 0, stream>>>(
      Xbf, YT, out, nullptr, nullptr, nullptr, 1024L * 2048, 2048L * 2048, 1024L * 2048);
}

// Round 3
// 366.730 us; speedup vs baseline: 1.2464x; 1.1035x over previous
//
#include <hip/hip_runtime.h>
#include <hip/hip_bf16.h>

typedef __bf16 v8bf __attribute__((ext_vector_type(8)));
typedef __bf16 v4bf __attribute__((ext_vector_type(4)));
typedef float  v4f  __attribute__((ext_vector_type(4)));

#define AS1 __attribute__((address_space(1)))
#define AS3 __attribute__((address_space(3)))

static __device__ __forceinline__ void gload_lds16(const void* g, void* l) {
  __builtin_amdgcn_global_load_lds((const AS1 void*)g, (AS3 void*)l, 16, 0, 0);
}

// ---- elementwise fp32 -> bf16 (n multiple of 4) ----
__global__ __launch_bounds__(256)
void cvt_bf16(const float* __restrict__ in, __bf16* __restrict__ out, long n) {
  const long i = ((long)blockIdx.x * 256 + threadIdx.x) * 4;
  if (i >= n) return;
  v4f v = *(const v4f*)&in[i];
  v4bf o;
#pragma unroll
  for (int u = 0; u < 4; ++u) o[u] = (__bf16)v[u];
  *(v4bf*)&out[i] = o;
}

// ---- zero fp32 buffer (n multiple of 1024 per grid covering) ----
__global__ __launch_bounds__(256)
void zero_f32(float* __restrict__ p, long n) {
  const long i = ((long)blockIdx.x * 256 + threadIdx.x) * 4;
  if (i >= n) return;
  *(v4f*)&p[i] = v4f{0.f, 0.f, 0.f, 0.f};
}

// ---- X [n][c][b] fp32 -> XT [n][b][c] bf16, 64x64 tiles via LDS ----
__global__ __launch_bounds__(256)
void cvt_transpose(const float* __restrict__ X, __bf16* __restrict__ XT) {
  __shared__ float t[64][65];
  const int b0 = blockIdx.x * 64, c0 = blockIdx.y * 64;
  const long n = blockIdx.z;
  const float* Xp = X + n * (1024L * 2048);
  __bf16* Tp = XT + n * (2048L * 1024);
  const int tid = threadIdx.x;
  const int r16 = tid >> 4, c4 = (tid & 15) * 4;
#pragma unroll
  for (int it = 0; it < 4; ++it) {
    const int r = r16 + it * 16;   // local c
    *(v4f*)&t[r][c4] = *(const v4f*)&Xp[(long)(c0 + r) * 2048 + b0 + c4];
  }
  __syncthreads();
  const int rb8 = tid >> 3, c8 = (tid & 7) * 8;
#pragma unroll
  for (int it = 0; it < 2; ++it) {
    const int rb = rb8 + it * 32;  // local b
    v8bf o;
#pragma unroll
    for (int u = 0; u < 8; ++u) o[u] = (__bf16)t[c8 + u][rb];
    *(v8bf*)&Tp[(long)(b0 + rb) * 1024 + c0 + c8] = o;
  }
}

// ---- 256x256 TN GEMM, 8-phase, single barrier/phase, counted vmcnt ----
// 8 waves (4x2), BK=64, double-buffered LDS (128 KiB), XOR-swizzled slots.
// Phase = [ds_read one half][stage one half-tile][lgkmcnt(0)][vmcnt@4/8][BAR]
//         [setprio 16xMFMA]. Quadrants (0,0)->(1,0)->(1,1)->(0,1): re-read
// is the 4-instr A-half. Swapped mfma(bf,af): acc reg-quad = 4 consecutive
// cols -> vectorized stores. XCD-chunked blockIdx swizzle (nwg%8==0).
// EPI 0: += bias[col], clamp +-32, atomic rownorm -> dk2[row]
// EPI 1: *= rsqrt(max(dk2[row]*dq2[col],eps)), clamp +-4 ; EPI 2: clamp +-1.
#define BAR __builtin_amdgcn_s_barrier()
#define LGKM0 do { asm volatile("s_waitcnt lgkmcnt(0)" ::: "memory"); \
                   __builtin_amdgcn_sched_barrier(0); } while (0)
#define VMW(N) do { asm volatile("s_waitcnt vmcnt(" #N ")" ::: "memory"); \
                    __builtin_amdgcn_sched_barrier(0); } while (0)
#define MM(HM, HN) do { \
  __builtin_amdgcn_s_setprio(1); \
  _Pragma("unroll") for (int ks = 0; ks < 2; ++ks) \
  _Pragma("unroll") for (int u = 0; u < 2; ++u) \
  _Pragma("unroll") for (int j = 0; j < 4; ++j) \
    acc[2 * (HM) + u][4 * (HN) + j] = __builtin_amdgcn_mfma_f32_16x16x32_bf16( \
        bfr[j][ks], af[u][ks], acc[2 * (HM) + u][4 * (HN) + j], 0, 0, 0); \
  __builtin_amdgcn_s_setprio(0); } while (0)

template<int KD, int EPI, typename OT>
__global__ __launch_bounds__(512, 2)
void gemm256(const __bf16* __restrict__ Abase, const __bf16* __restrict__ Bbase,
             OT* __restrict__ Obase, const __bf16* __restrict__ bias,
             float* __restrict__ dk2, const float* __restrict__ dq2,
             long sA, long sB, long sO) {
  // buf0 (even tiles): A[256][64] @0, B @16384; buf1 (odd tiles) @32768.
  __shared__ __align__(128) __bf16 lds[65536];

  const int tid = threadIdx.x;
  const int wave = tid >> 6, lane = tid & 63;
  const int qr = wave >> 1, qc = wave & 1;      // 4x2 wave grid
  const int fr = lane & 15, q = lane >> 4;
  const int f7 = fr & 7;

  // XCD-chunked bijective swizzle (nwg divisible by 8)
  const int gx = gridDim.x, gy = gridDim.y;
  int id = blockIdx.x + gx * (blockIdx.y + gy * blockIdx.z);
  const int chunk = (gx * gy * gridDim.z) >> 3;
  id = (id & 7) * chunk + (id >> 3);
  const int bx = id % gx;
  const int rem = id / gx;
  const int by = rem % gy;
  const long z = rem / gy;

  const int n0 = bx * 256, m0 = by * 256;
  const __bf16* A = Abase + z * sA + (long)m0 * KD;
  const __bf16* B = Bbase + z * sB + (long)n0 * KD;

  // staging: wave w, instr i covers rows [half*128 + w*16 + i*8, +8);
  // lane l -> row +(l>>3), slot (l&7) holds k-chunk ((l&7)^(l>>3)).
  const int lrow = wave * 16 + (lane >> 3);
  const int lchunk = ((lane & 7) ^ (lane >> 3)) << 3;
  const __bf16* Alane = A + (long)lrow * KD + lchunk;
  const __bf16* Blane = B + (long)lrow * KD + lchunk;
  const int dbase = wave * 1024;

  auto stage = [&](int kt, int isB, int half) {
    const __bf16* gp = (isB ? Blane : Alane) + (long)(half * 128) * KD + kt * 64;
    __bf16* dp = lds + (kt & 1) * 32768 + isB * 16384 + half * 8192 + dbase;
    gload_lds16(gp, dp);
    gload_lds16(gp + (long)8 * KD, dp + 512);
  };

  v4f acc[4][8];
#pragma unroll
  for (int i = 0; i < 4; ++i)
#pragma unroll
    for (int j = 0; j < 8; ++j) acc[i][j] = {0.f, 0.f, 0.f, 0.f};

  v8bf af[2][2], bfr[4][2];
  auto readA = [&](const __bf16* sa, int hm) {
#pragma unroll
    for (int u = 0; u < 2; ++u) {
      const int rb = (hm * 128 + qr * 32 + u * 16 + fr) * 64;
      af[u][0] = *(const v8bf*)&sa[rb + ((q ^ f7) << 3)];
      af[u][1] = *(const v8bf*)&sa[rb + (((q | 4) ^ f7) << 3)];
    }
  };
  auto readB = [&](const __bf16* sb, int hn) {
#pragma unroll
    for (int j = 0; j < 4; ++j) {
      const int rb = (hn * 128 + qc * 64 + j * 16 + fr) * 64;
      bfr[j][0] = *(const v8bf*)&sb[rb + ((q ^ f7) << 3)];
      bfr[j][1] = *(const v8bf*)&sb[rb + (((q | 4) ^ f7) << 3)];
    }
  };

  constexpr int NT = KD / 64;
  constexpr int NI = NT / 2;
  __bf16* s0 = lds;
  __bf16* s1 = lds + 32768;

  // prologue: tile0 all 4 halves + tile1 {B0,A1,B1}; tile1.A0 is JIT at ph1.
  stage(0, 0, 0); stage(0, 1, 0); stage(0, 0, 1); stage(0, 1, 1);
  stage(1, 1, 0); stage(1, 0, 1); stage(1, 1, 1);
  VMW(6); BAR;

#pragma unroll 1
  for (int m = 0; m < NI; ++m) {
    const bool nl = (m != NI - 1);
    const int t1 = 2 * m + 1, t2 = 2 * m + 2, t3 = 2 * m + 3;
    // ph1: reads s0.A0,B0 ; stage s1.A0 (tile t1, JIT)
    readA(s0, 0); readB(s0 + 16384, 0);
    stage(t1, 0, 0);
    LGKM0; BAR; MM(0, 0);
    // ph2: reads s0.A1 (B0 held); stage s0.B0 (t2)
    readA(s0, 1);
    if (nl) stage(t2, 1, 0);
    LGKM0; BAR; MM(1, 0);
    // ph3: reads s0.B1 (A1 held); stage s0.A1 (t2)
    readB(s0 + 16384, 1);
    if (nl) stage(t2, 0, 1);
    LGKM0; BAR; MM(1, 1);
    // ph4: re-read s0.A0 (B1 held); stage s0.B1 (t2); counted vmcnt
    readA(s0, 0);
    if (nl) stage(t2, 1, 1);
    LGKM0;
    if (nl) { VMW(6); } else { VMW(0); }
    BAR; MM(0, 1);
    // ph5: reads s1.A0,B0 ; stage s0.A0 (t2)
    readA(s1, 0); readB(s1 + 16384, 0);
    if (nl) stage(t2, 0, 0);
    LGKM0; BAR; MM(0, 0);
    // ph6: reads s1.A1 ; stage s1.B0 (t3)
    readA(s1, 1);
    if (nl) stage(t3, 1, 0);
    LGKM0; BAR; MM(1, 0);
    // ph7: reads s1.B1 ; stage s1.A1 (t3)
    readB(s1 + 16384, 1);
    if (nl) stage(t3, 0, 1);
    LGKM0; BAR; MM(1, 1);
    // ph8: re-read s1.A0 ; stage s1.B1 (t3); counted vmcnt
    readA(s1, 0);
    if (nl) stage(t3, 1, 1);
    LGKM0;
    if (nl) { VMW(6); } else { VMW(0); }
    BAR; MM(0, 1);
  }

  // Epilogue. Swapped-operand C layout: thread holds, for acc[ai][bj] reg r:
  //   row = m0 + (ai>>1)*128 + qr*32 + (ai&1)*16 + fr
  //   col = n0 + (bj>>2)*128 + qc*64 + (bj&3)*16 + q*4 + r   (r contiguous)
  OT* O = Obase + z * sO;
  const int ldo = gx * 256;
#pragma unroll
  for (int ai = 0; ai < 4; ++ai) {
    const int row = m0 + (ai >> 1) * 128 + qr * 32 + (ai & 1) * 16 + fr;
    float rk = 0.f;
    if (EPI == 1) rk = dk2[z * 2048 + row];
    float rs = 0.f;
#pragma unroll
    for (int bj = 0; bj < 8; ++bj) {
      const int colb = n0 + (bj >> 2) * 128 + qc * 64 + (bj & 3) * 16 + q * 4;
      float cv[4];
      if (EPI == 0) {
        v4bf bb = *(const v4bf*)&bias[colb];
#pragma unroll
        for (int r = 0; r < 4; ++r) cv[r] = (float)bb[r];
      }
      if (EPI == 1) {
        v4f dd = *(const v4f*)&dq2[z * 2048 + colb];
#pragma unroll
        for (int r = 0; r < 4; ++r) cv[r] = dd[r];
      }
      float vv[4];
#pragma unroll
      for (int r = 0; r < 4; ++r) {
        float v = acc[ai][bj][r];
        if (EPI == 0) {
          v = fminf(fmaxf(v + cv[r], -32.f), 32.f);
          rs += v * v;
        }
        if (EPI == 1) {
          v *= rsqrtf(fmaxf(rk * cv[r], 1e-12f));
          v = fminf(fmaxf(v, -4.f), 4.f);
        }
        if (EPI == 2) v = fminf(fmaxf(v, -1.f), 1.f);
        vv[r] = v;
      }
      if (sizeof(OT) == 2) {
        v4bf o;
#pragma unroll
        for (int r = 0; r < 4; ++r) o[r] = (__bf16)vv[r];
        *(v4bf*)&O[(long)row * ldo + colb] = o;
      } else {
        v4f o;
#pragma unroll
        for (int r = 0; r < 4; ++r) o[r] = vv[r];
        *(v4f*)&O[(long)row * ldo + colb] = o;
      }
    }
    if (EPI == 0) {
      // reduce row-sum-of-squares over the 4 q-lanes sharing this row
      rs += __shfl_xor(rs, 16);
      rs += __shfl_xor(rs, 32);
      if (q == 0) atomicAdd(&dk2[z * 2048 + row], rs);
    }
  }
}

// ---- in-place row softmax over 2048 bf16 (|Y|<=4: no max pass) ----
__global__ __launch_bounds__(256)
void softmax_rows(__bf16* __restrict__ Y) {
  const int tid = threadIdx.x;
  const long row = (long)blockIdx.y * gridDim.x + blockIdx.x;
  __bf16* p = Y + row * 2048;
  v8bf v = *(const v8bf*)&p[tid * 8];
  float f[8];
  float s = 0.f;
#pragma unroll
  for (int u = 0; u < 8; ++u) { f[u] = __expf((float)v[u]); s += f[u]; }
#pragma unroll
  for (int off = 32; off > 0; off >>= 1) s += __shfl_down(s, off);
  __shared__ float red[4];
  __shared__ float stot;
  if ((tid & 63) == 0) red[tid >> 6] = s;
  __syncthreads();
  if (tid == 0) stot = 1.f / (red[0] + red[1] + red[2] + red[3]);
  __syncthreads();
  const float inv = stot;
  v8bf o;
#pragma unroll
  for (int u = 0; u < 8; ++u) o[u] = (__bf16)(f[u] * inv);
  *(v8bf*)&p[tid * 8] = o;
}

extern "C" void kernel_launch(void* const* d_in, const int* in_sizes, int n_in,
                              void* d_out, int out_size, void* d_ws, size_t ws_size,
                              hipStream_t stream) {
  const float* X    = (const float*)d_in[0];
  const float* Wk_w = (const float*)d_in[1];
  const float* Wk_b = (const float*)d_in[2];
  const float* Wq_w = (const float*)d_in[3];
  const float* Wq_b = (const float*)d_in[4];
  float* out = (float*)d_out;

  // ws: [0,32M): XT bf16 [n][b][c] -> later Xbf bf16 [n][c][b]
  //     [32M,96M): YT bf16 [n][k][b]
  //     [96M+): DK2, DQ2, Wk_bf, Wq_bf, bk_bf, bq_bf
  char* ws = (char*)d_ws;
  __bf16* XT  = (__bf16*)(ws);
  __bf16* Xbf = (__bf16*)(ws);
  __bf16* YT  = (__bf16*)(ws + 33554432L);
  char* aux   = ws + 100663296L;
  float*  DK2   = (float*)(aux);
  float*  DQ2   = (float*)(aux + 65536L);
  __bf16* Wk_bf = (__bf16*)(aux + 131072L);
  __bf16* Wq_bf = (__bf16*)(aux + 131072L + 2097152L);
  __bf16* bk_bf = (__bf16*)(aux + 131072L + 4194304L);
  __bf16* bq_bf = (__bf16*)(aux + 131072L + 4196352L);
  // d_out (64 MiB) holds KT|QT until GEMM3 overwrites it with Z.
  __bf16* KT = (__bf16*)d_out;
  __bf16* QT = (__bf16*)((char*)d_out + 33554432L);

  // 0) convert weights/biases to bf16; zero DK2|DQ2 (contiguous 128 KiB)
  cvt_bf16<<<1024, 256, 0, stream>>>(Wk_w, Wk_bf, 1048576L);
  cvt_bf16<<<1024, 256, 0, stream>>>(Wq_w, Wq_bf, 1048576L);
  cvt_bf16<<<1, 256, 0, stream>>>(Wk_b, bk_bf, 1024L);
  cvt_bf16<<<1, 256, 0, stream>>>(Wq_b, bq_bf, 1024L);
  zero_f32<<<32, 256, 0, stream>>>(DK2, 32768L);
  // 1) XT[n][b][c] = (bf16) X[n][c][b]
  cvt_transpose<<<dim3(32, 16, 8), 256, 0, stream>>>(X, XT);
  // 2) KT[n][b][o] = XT[b,:]·Wk[o,:] + bk[o]; fused rownorm -> DK2; same for Q
  gemm256<1024, 0, __bf16><<<dim3(4, 8, 8), 512, 0, stream>>>(
      XT, Wk_bf, KT, bk_bf, DK2, nullptr, 2048L * 1024, 0L, 2048L * 1024);
  gemm256<1024, 0, __bf16><<<dim3(4, 8, 8), 512, 0, stream>>>(
      XT, Wq_bf, QT, bq_bf, DQ2, nullptr, 2048L * 1024, 0L, 2048L * 1024);
  // 3) Xbf = (bf16) X  (XT dead; same ws region)
  cvt_bf16<<<16384, 256, 0, stream>>>(X, Xbf, 16777216L);
  // 4) YT[n][k][b] = (KT[k,:]·QT[b,:]) * rsqrt(max(DK2[k]*DQ2[b],eps))
  gemm256<1024, 1, __bf16><<<dim3(8, 8, 8), 512, 0, stream>>>(
      KT, QT, YT, nullptr, DK2, DQ2, 2048L * 1024, 2048L * 1024, 2048L * 2048);
  // 5) softmax over b within each YT row (ref softmax over query axis)
  softmax_rows<<<dim3(2048, 8), 256, 0, stream>>>(YT);
  // 6) Z[n][c][k] = Xbf[c,:]·SMT[k,:]  (sum over b) -> d_out fp32
  gemm256<2048, 2, float><<<dim3(8, 4, 8), 512, 0, stream>>>(
      Xbf, YT, out, nullptr, nullptr, nullptr, 1024L * 2048, 2048L * 2048, 1024L * 2048);
}